// Round 2
// baseline (235.936 us; speedup 1.0000x reference)
//
#include <hip/hip_runtime.h>
#include <cstdint>

// Problem constants (fixed by reference setup_inputs)
#define BB 16
#define NN 65536
#define DD 32
#define KK 64
#define DELTA_V 0.5f
#define DELTA_D 1.5f
#define BPB 64            // blocks per batch for the big passes
#define PPB (NN / BPB)    // points per block = 1024

// ---------------------------------------------------------------------------
// Kernel 1: per-(batch,instance) sums + counts via LDS atomics + global flush
// ---------------------------------------------------------------------------
__global__ __launch_bounds__(256) void k_accum(
    const float* __restrict__ emb, const int* __restrict__ ids,
    const int* __restrict__ mask, float* __restrict__ sums,
    float* __restrict__ counts)
{
    __shared__ float ls[KK][DD + 1];   // +1 pad: bank = (id + d) % 32
    __shared__ float lc[KK];
    const int tid = threadIdx.x;
    for (int i = tid; i < KK * (DD + 1); i += 256) ((float*)ls)[i] = 0.f;
    if (tid < KK) lc[tid] = 0.f;
    __syncthreads();

    const int b   = blockIdx.x >> 6;   // blockIdx.x / BPB
    const int blk = blockIdx.x & 63;
    const size_t base = (size_t)b * NN;

    for (int p = blk * PPB + tid; p < blk * PPB + PPB; p += 256) {
        const int id = ids[base + p];
        const bool v = (mask[base + p] != 0) && (id >= 0) && (id < KK);
        if (v) {
            const float4* e = (const float4*)(emb + (base + p) * DD);
            float vals[DD];
#pragma unroll
            for (int q = 0; q < 8; ++q) {
                float4 t = e[q];
                vals[4 * q + 0] = t.x; vals[4 * q + 1] = t.y;
                vals[4 * q + 2] = t.z; vals[4 * q + 3] = t.w;
            }
            float* row = ls[id];
#pragma unroll
            for (int d = 0; d < DD; ++d) atomicAdd(&row[d], vals[d]);
            atomicAdd(&lc[id], 1.f);
        }
    }
    __syncthreads();

    float* gs = sums + (size_t)b * KK * DD;
    for (int i = tid; i < KK * DD; i += 256) {
        const float v = ls[i >> 5][i & 31];
        if (v != 0.f) atomicAdd(&gs[i], v);
    }
    if (tid < KK) {
        const float v = lc[tid];
        if (v != 0.f) atomicAdd(&counts[b * KK + tid], v);
    }
}

// ---------------------------------------------------------------------------
// Kernel 2: per-batch reg loss + pairwise push loss (tiny)
// ---------------------------------------------------------------------------
__global__ __launch_bounds__(256) void k_push_reg(
    const float* __restrict__ sums, const float* __restrict__ counts,
    float* __restrict__ regb, float* __restrict__ distb)
{
    const int b = blockIdx.x;
    const int tid = threadIdx.x;
    __shared__ float lm[KK][DD + 1];
    __shared__ float lcnt[KK];
    __shared__ float red[4];

    if (tid < KK) lcnt[tid] = counts[b * KK + tid];
    __syncthreads();

    const float* gs = sums + (size_t)b * KK * DD;
    for (int i = tid; i < KK * DD; i += 256) {
        const int k = i >> 5, d = i & 31;
        lm[k][d] = gs[i] / fmaxf(lcnt[k], 1.f);
    }
    __syncthreads();

    // reg loss + num_inst (one wave: tid < 64)
    float ninst = 0.f;   // valid on tid 0 after reduce
    if (tid < KK) {
        const float c = lcnt[tid];
        const float pres = (c > 0.f) ? 1.f : 0.f;
        float sq = 0.f;
#pragma unroll
        for (int d = 0; d < DD; ++d) { const float m = lm[tid][d]; sq = fmaf(m, m, sq); }
        float nm = ((sq > 0.f) ? sqrtf(sq) : 0.f) * pres;
        float pn = pres;
        for (int off = 32; off; off >>= 1) {
            pn += __shfl_down(pn, off);
            nm += __shfl_down(nm, off);
        }
        if (tid == 0) {
            ninst = pn;
            regb[b] = nm / fmaxf(pn, 1.f);
        }
    }

    // pairwise push loss over K*K grid, keep i<j
    float acc = 0.f;
    for (int idx = tid; idx < KK * KK; idx += 256) {
        const int i = idx >> 6, j = idx & 63;
        if (i < j && lcnt[i] > 0.f && lcnt[j] > 0.f) {
            float dsq = 0.f;
#pragma unroll
            for (int d = 0; d < DD; ++d) {
                const float df = lm[i][d] - lm[j][d];
                dsq = fmaf(df, df, dsq);
            }
            const float pd = (dsq > 0.f) ? sqrtf(dsq) : 0.f;
            const float pen = fmaxf(2.f * DELTA_D - pd, 0.f);
            acc = fmaf(pen, pen, acc);
        }
    }
    for (int off = 32; off; off >>= 1) acc += __shfl_down(acc, off);
    if ((tid & 63) == 0) red[tid >> 6] = acc;
    __syncthreads();
    if (tid == 0) {
        const float tot = red[0] + red[1] + red[2] + red[3];
        const float np = ninst * (ninst - 1.f) * 0.5f;
        distb[b] = tot / fmaxf(np, 1.f);
    }
}

// ---------------------------------------------------------------------------
// Kernel 3: pull (variance) penalty pass — means recomputed into LDS
// ---------------------------------------------------------------------------
__global__ __launch_bounds__(256) void k_pull(
    const float* __restrict__ emb, const int* __restrict__ ids,
    const int* __restrict__ mask, const float* __restrict__ sums,
    const float* __restrict__ counts, float* __restrict__ inst_pen)
{
    __shared__ float lm[KK][DD + 1];
    __shared__ float lp[KK];
    const int tid = threadIdx.x;
    const int b   = blockIdx.x >> 6;
    const int blk = blockIdx.x & 63;

    const float* gs = sums + (size_t)b * KK * DD;
    const float* gc = counts + b * KK;
    for (int i = tid; i < KK * DD; i += 256) {
        const int k = i >> 5, d = i & 31;
        lm[k][d] = gs[i] / fmaxf(gc[k], 1.f);
    }
    if (tid < KK) lp[tid] = 0.f;
    __syncthreads();

    const size_t base = (size_t)b * NN;
    for (int p = blk * PPB + tid; p < blk * PPB + PPB; p += 256) {
        const int id = ids[base + p];
        const bool v = (mask[base + p] != 0) && (id >= 0) && (id < KK);
        if (v) {
            const float4* e = (const float4*)(emb + (base + p) * DD);
            const float* mr = lm[id];
            float dsq = 0.f;
#pragma unroll
            for (int q = 0; q < 8; ++q) {
                const float4 t = e[q];
                float a;
                a = t.x - mr[4 * q + 0]; dsq = fmaf(a, a, dsq);
                a = t.y - mr[4 * q + 1]; dsq = fmaf(a, a, dsq);
                a = t.z - mr[4 * q + 2]; dsq = fmaf(a, a, dsq);
                a = t.w - mr[4 * q + 3]; dsq = fmaf(a, a, dsq);
            }
            const float dist = (dsq > 0.f) ? sqrtf(dsq) : 0.f;
            const float pen = fmaxf(dist - DELTA_V, 0.f);
            atomicAdd(&lp[id], pen * pen);
        }
    }
    __syncthreads();
    if (tid < KK) {
        const float v = lp[tid];
        if (v != 0.f) atomicAdd(&inst_pen[b * KK + tid], v);
    }
}

// ---------------------------------------------------------------------------
// Kernel 4: final combine -> 4 outputs
// ---------------------------------------------------------------------------
__global__ __launch_bounds__(64) void k_final(
    const float* __restrict__ counts, const float* __restrict__ inst_pen,
    const float* __restrict__ regb, const float* __restrict__ distb,
    float* __restrict__ out)
{
    const int tid = threadIdx.x;
    __shared__ float s_var[BB], s_valid[BB];
    if (tid < BB) {
        const int b = tid;
        float vn = 0.f, ni = 0.f;
        for (int k = 0; k < KK; ++k) {
            const float c = counts[b * KK + k];
            if (c > 0.f) { ni += 1.f; vn += inst_pen[b * KK + k] / c; }
        }
        s_var[tid]   = vn / fmaxf(ni, 1.f);
        s_valid[tid] = (ni >= 2.f) ? 1.f : 0.f;
    }
    __syncthreads();
    if (tid == 0) {
        float denom = 0.f, v = 0.f, d = 0.f, r = 0.f;
        for (int b = 0; b < BB; ++b) {
            const float vb = s_valid[b];
            denom += vb;
            v += s_var[b] * vb;
            d += distb[b] * vb;
            r += regb[b] * vb;
        }
        denom = fmaxf(denom, 1.f);
        v /= denom; d /= denom; r /= denom;
        out[0] = v + d + 0.001f * r;   // ALPHA=BETA=1, GAMMA=0.001
        out[1] = v;
        out[2] = d;
        out[3] = r;
    }
}

// ---------------------------------------------------------------------------
extern "C" void kernel_launch(void* const* d_in, const int* in_sizes, int n_in,
                              void* d_out, int out_size, void* d_ws, size_t ws_size,
                              hipStream_t stream)
{
    const float* emb  = (const float*)d_in[0];
    const int*   ids  = (const int*)d_in[1];
    const int*   mask = (const int*)d_in[2];   // bool widened to int32 by harness

    float* ws     = (float*)d_ws;
    float* sums   = ws;                               // 32768
    float* counts = sums + (size_t)BB * KK * DD;      // 1024
    float* ipen   = counts + BB * KK;                 // 1024
    float* regb   = ipen + BB * KK;                   // 16
    float* distb  = regb + BB;                        // 16

    // zero the atomic accumulators (sums + counts + ipen are contiguous)
    hipMemsetAsync(sums, 0, (size_t)(BB * KK * DD + 2 * BB * KK) * sizeof(float),
                   stream);

    k_accum<<<BB * BPB, 256, 0, stream>>>(emb, ids, mask, sums, counts);
    k_push_reg<<<BB, 256, 0, stream>>>(sums, counts, regb, distb);
    k_pull<<<BB * BPB, 256, 0, stream>>>(emb, ids, mask, sums, counts, ipen);
    k_final<<<1, 64, 0, stream>>>(counts, ipen, regb, distb, (float*)d_out);
}

// Round 3
// 168.162 us; speedup vs baseline: 1.4030x; 1.4030x over previous
//
#include <hip/hip_runtime.h>
#include <cstdint>

#define BB 16
#define NN 65536
#define DD 32
#define KK 64
#define DELTA_V 0.5f
#define DELTA_D 1.5f

// ---------------------------------------------------------------------------
// Kernel 1: per-(batch,instance) sums + counts. Atomic-free: per-wave LDS
// tables, pair-scan with readlane-broadcast ids, exclusive plain RMW.
// ---------------------------------------------------------------------------
#define K1_BPB 32                    // blocks per batch
#define K1_PTS (NN / K1_BPB)         // 2048 points per block
#define K1_WPTS (K1_PTS / 4)         // 512 points per wave

__global__ __launch_bounds__(256) void k_accum(
    const float* __restrict__ emb, const int* __restrict__ ids,
    const int* __restrict__ mask, float* __restrict__ sums,
    float* __restrict__ counts)
{
    __shared__ float lsv[4][KK][DD];   // 32 KB: per-wave sum tables
    __shared__ float lcn[4][KK];       // 1 KB : per-wave count tables
    const int tid = threadIdx.x;
    const int w = tid >> 6, lane = tid & 63;
    for (int i = tid; i < 4 * KK * DD; i += 256) ((float*)lsv)[i] = 0.f;
    for (int i = tid; i < 4 * KK; i += 256) ((float*)lcn)[i] = 0.f;
    __syncthreads();

    const int b   = blockIdx.x >> 5;   // / K1_BPB
    const int blk = blockIdx.x & 31;
    const size_t p0 = (size_t)b * NN + (size_t)blk * K1_PTS + (size_t)w * K1_WPTS;

    const int half = lane >> 5;        // 0: point j, 1: point j+1
    const int d    = lane & 31;
    float (*tbl)[DD] = lsv[w];
    float* cnt = lcn[w];

    for (int c = 0; c < K1_WPTS; c += 64) {
        const int idv = ids[p0 + c + lane];
        const int mkv = mask[p0 + c + lane];
        const float* erow = emb + (p0 + c) * DD + lane;  // lane == half*32+d
#pragma unroll 8
        for (int j = 0; j < 64; j += 2) {
            const int sid1 = __builtin_amdgcn_readlane(idv, j);
            const int sid2 = __builtin_amdgcn_readlane(idv, j + 1);
            const int m1   = __builtin_amdgcn_readlane(mkv, j);
            const int m2   = __builtin_amdgcn_readlane(mkv, j + 1);
            const bool v1 = m1 && ((unsigned)sid1 < KK);
            const bool v2 = m2 && ((unsigned)sid2 < KK);
            const int r1 = v1 ? sid1 : 0;
            const int r2 = v2 ? sid2 : 0;
            // rows j (lanes 0-31) and j+1 (lanes 32-63), coalesced 256B
            float x = erow[j * DD];
            const bool act = half ? v2 : v1;
            x = act ? x : 0.f;
            if (r1 == r2) {            // uniform condition -> scalar branch
                const float xh = __shfl_down(x, 32);
                if (half == 0) tbl[r1][d] += x + xh;
                if (lane == 0) cnt[r1] += (v1 ? 1.f : 0.f) + (v2 ? 1.f : 0.f);
            } else {                   // distinct rows: exclusive addresses
                const int r = half ? r2 : r1;
                tbl[r][d] += x;        // adds 0 when inactive
                if (lane == 0 || lane == 32) cnt[r] += (act ? 1.f : 0.f);
            }
        }
    }
    __syncthreads();

    float* gs = sums + (size_t)b * KK * DD;
    for (int i = tid; i < KK * DD; i += 256) {
        const float s = ((const float*)lsv[0])[i] + ((const float*)lsv[1])[i]
                      + ((const float*)lsv[2])[i] + ((const float*)lsv[3])[i];
        atomicAdd(&gs[i], s);
    }
    if (tid < KK)
        atomicAdd(&counts[b * KK + tid],
                  lcn[0][tid] + lcn[1][tid] + lcn[2][tid] + lcn[3][tid]);
}

// ---------------------------------------------------------------------------
// Kernel 2: pull (variance) pass. Transposed means in LDS (conflict-light),
// per-thread-private LDS pen rows (no atomics), column-reduce + global flush.
// ---------------------------------------------------------------------------
#define K2_BPB 64                    // blocks per batch
#define K2_PTS (NN / K2_BPB)         // 1024 points per block

__global__ __launch_bounds__(128) void k_pull(
    const float* __restrict__ emb, const int* __restrict__ ids,
    const int* __restrict__ mask, const float* __restrict__ sums,
    const float* __restrict__ counts, float* __restrict__ ipen)
{
    __shared__ float mu[DD][KK];        // 8 KB transposed means
    __shared__ float lpp[128][KK + 1];  // 33.3 KB per-thread pen rows
    const int tid = threadIdx.x;
    const int b   = blockIdx.x >> 6;    // / K2_BPB
    const int blk = blockIdx.x & 63;

    const float* gs = sums + (size_t)b * KK * DD;
    const float* gc = counts + b * KK;
    for (int i = tid; i < KK * DD; i += 128) {
        const int k = i & 63, dd = i >> 6;
        mu[dd][k] = gs[k * DD + dd] / fmaxf(gc[k], 1.f);
    }
    for (int i = tid; i < 128 * (KK + 1); i += 128) ((float*)lpp)[i] = 0.f;
    __syncthreads();

    const size_t p0 = (size_t)b * NN + (size_t)blk * K2_PTS;
    float* myrow = lpp[tid];
    for (int p = tid; p < K2_PTS; p += 128) {
        const int id = ids[p0 + p];
        const bool v = (mask[p0 + p] != 0) && ((unsigned)id < KK);
        const int sid = v ? id : 0;
        const float4* e = (const float4*)(emb + (p0 + p) * DD);
        float dsq = 0.f;
#pragma unroll
        for (int q = 0; q < 8; ++q) {
            const float4 t = e[q];
            float a;
            a = t.x - mu[4 * q + 0][sid]; dsq = fmaf(a, a, dsq);
            a = t.y - mu[4 * q + 1][sid]; dsq = fmaf(a, a, dsq);
            a = t.z - mu[4 * q + 2][sid]; dsq = fmaf(a, a, dsq);
            a = t.w - mu[4 * q + 3][sid]; dsq = fmaf(a, a, dsq);
        }
        const float dist = (dsq > 0.f) ? sqrtf(dsq) : 0.f;
        float pen = fmaxf(dist - DELTA_V, 0.f);
        pen = pen * pen;
        if (v) myrow[sid] += pen;     // exclusive per-thread row, plain RMW
    }
    __syncthreads();
    if (tid < KK) {
        float s = 0.f;
        for (int r = 0; r < 128; ++r) s += lpp[r][tid];  // conflict-free (+1 pad)
        atomicAdd(&ipen[b * KK + tid], s);
    }
}

// ---------------------------------------------------------------------------
// Kernel 3: per-batch reg loss + pairwise push loss (tiny)
// ---------------------------------------------------------------------------
__global__ __launch_bounds__(256) void k_push_reg(
    const float* __restrict__ sums, const float* __restrict__ counts,
    float* __restrict__ regb, float* __restrict__ distb)
{
    const int b = blockIdx.x;
    const int tid = threadIdx.x;
    __shared__ float lm[KK][DD + 1];
    __shared__ float lcnt[KK];
    __shared__ float red[4];

    if (tid < KK) lcnt[tid] = counts[b * KK + tid];
    __syncthreads();

    const float* gs = sums + (size_t)b * KK * DD;
    for (int i = tid; i < KK * DD; i += 256) {
        const int k = i >> 5, d = i & 31;
        lm[k][d] = gs[i] / fmaxf(lcnt[k], 1.f);
    }
    __syncthreads();

    float ninst = 0.f;
    if (tid < KK) {
        const float c = lcnt[tid];
        const float pres = (c > 0.f) ? 1.f : 0.f;
        float sq = 0.f;
#pragma unroll
        for (int d = 0; d < DD; ++d) { const float m = lm[tid][d]; sq = fmaf(m, m, sq); }
        float nm = ((sq > 0.f) ? sqrtf(sq) : 0.f) * pres;
        float pn = pres;
        for (int off = 32; off; off >>= 1) {
            pn += __shfl_down(pn, off);
            nm += __shfl_down(nm, off);
        }
        if (tid == 0) {
            ninst = pn;
            regb[b] = nm / fmaxf(pn, 1.f);
        }
    }

    float acc = 0.f;
    for (int idx = tid; idx < KK * KK; idx += 256) {
        const int i = idx >> 6, j = idx & 63;
        if (i < j && lcnt[i] > 0.f && lcnt[j] > 0.f) {
            float dsq = 0.f;
#pragma unroll
            for (int d = 0; d < DD; ++d) {
                const float df = lm[i][d] - lm[j][d];
                dsq = fmaf(df, df, dsq);
            }
            const float pd = (dsq > 0.f) ? sqrtf(dsq) : 0.f;
            const float pen = fmaxf(2.f * DELTA_D - pd, 0.f);
            acc = fmaf(pen, pen, acc);
        }
    }
    for (int off = 32; off; off >>= 1) acc += __shfl_down(acc, off);
    if ((tid & 63) == 0) red[tid >> 6] = acc;
    __syncthreads();
    if (tid == 0) {
        const float tot = red[0] + red[1] + red[2] + red[3];
        const float np = ninst * (ninst - 1.f) * 0.5f;
        distb[b] = tot / fmaxf(np, 1.f);
    }
}

// ---------------------------------------------------------------------------
// Kernel 4: final combine -> 4 outputs
// ---------------------------------------------------------------------------
__global__ __launch_bounds__(64) void k_final(
    const float* __restrict__ counts, const float* __restrict__ inst_pen,
    const float* __restrict__ regb, const float* __restrict__ distb,
    float* __restrict__ out)
{
    const int tid = threadIdx.x;
    __shared__ float s_var[BB], s_valid[BB];
    if (tid < BB) {
        const int b = tid;
        float vn = 0.f, ni = 0.f;
        for (int k = 0; k < KK; ++k) {
            const float c = counts[b * KK + k];
            if (c > 0.f) { ni += 1.f; vn += inst_pen[b * KK + k] / c; }
        }
        s_var[tid]   = vn / fmaxf(ni, 1.f);
        s_valid[tid] = (ni >= 2.f) ? 1.f : 0.f;
    }
    __syncthreads();
    if (tid == 0) {
        float denom = 0.f, v = 0.f, d = 0.f, r = 0.f;
        for (int b = 0; b < BB; ++b) {
            const float vb = s_valid[b];
            denom += vb;
            v += s_var[b] * vb;
            d += distb[b] * vb;
            r += regb[b] * vb;
        }
        denom = fmaxf(denom, 1.f);
        v /= denom; d /= denom; r /= denom;
        out[0] = v + d + 0.001f * r;   // ALPHA=BETA=1, GAMMA=0.001
        out[1] = v;
        out[2] = d;
        out[3] = r;
    }
}

// ---------------------------------------------------------------------------
extern "C" void kernel_launch(void* const* d_in, const int* in_sizes, int n_in,
                              void* d_out, int out_size, void* d_ws, size_t ws_size,
                              hipStream_t stream)
{
    const float* emb  = (const float*)d_in[0];
    const int*   ids  = (const int*)d_in[1];
    const int*   mask = (const int*)d_in[2];   // bool widened to int32

    float* ws     = (float*)d_ws;
    float* sums   = ws;                               // 32768
    float* counts = sums + (size_t)BB * KK * DD;      // 1024
    float* ipen   = counts + BB * KK;                 // 1024
    float* regb   = ipen + BB * KK;                   // 16
    float* distb  = regb + BB;                        // 16

    hipMemsetAsync(sums, 0, (size_t)(BB * KK * DD + 2 * BB * KK) * sizeof(float),
                   stream);

    k_accum<<<BB * K1_BPB, 256, 0, stream>>>(emb, ids, mask, sums, counts);
    k_pull<<<BB * K2_BPB, 128, 0, stream>>>(emb, ids, mask, sums, counts, ipen);
    k_push_reg<<<BB, 256, 0, stream>>>(sums, counts, regb, distb);
    k_final<<<1, 64, 0, stream>>>(counts, ipen, regb, distb, (float*)d_out);
}

// Round 4
// 98.897 us; speedup vs baseline: 2.3857x; 1.7004x over previous
//
#include <hip/hip_runtime.h>
#include <cstdint>

#define BB 16
#define NN 65536
#define DD 32
#define KK 64
#define DELTA_V 0.5f
#define DELTA_D 1.5f

typedef short bf16x8 __attribute__((ext_vector_type(8)));
typedef float f32x16 __attribute__((ext_vector_type(16)));

__device__ __forceinline__ short f2bf(float x) {
    union { float f; unsigned u; } v; v.f = x;
    const unsigned r = v.u + 0x7FFFu + ((v.u >> 16) & 1u);  // RNE
    return (short)(r >> 16);
}

// ---------------------------------------------------------------------------
// Kernel 1: per-(batch,instance) sums + counts as one-hot MFMA matmul.
//   sums[k][d] = sum_p onehot[k][p] * emb[p][d]  (A = one-hot, B = bf16 emb)
//   counts     = popcount of one-hot bits (exact, no MFMA needed)
// ---------------------------------------------------------------------------
#define K1_BPB 64                    // blocks per batch -> grid 1024
#define K1_PTS (NN / K1_BPB)         // 1024 points per block
#define K1_WPTS (K1_PTS / 4)         // 256 points per wave

__global__ __launch_bounds__(256) void k_accum(
    const float* __restrict__ emb, const int* __restrict__ ids,
    const int* __restrict__ mask, float* __restrict__ sums,
    float* __restrict__ counts)
{
    __shared__ float lws[4][KK][DD];   // 32 KB per-wave C tables (store-only)
    __shared__ int   lcnt[4][KK];
    __shared__ int   lid[4][64];       // per-wave staged validated ids
    const int tid  = threadIdx.x;
    const int w    = tid >> 6, lane = tid & 63;
    const int half = lane >> 5, d32 = lane & 31;
    const int b    = blockIdx.x >> 6;        // / K1_BPB
    const int blk  = blockIdx.x & 63;
    const size_t pw = (size_t)b * NN + (size_t)blk * K1_PTS + (size_t)w * K1_WPTS;

    f32x16 acc0 = {}, acc1 = {};
    int c0 = 0, c1 = 0;
    const int m0 = d32, m1 = d32 + 32;

    for (int c = 0; c < K1_WPTS; c += 64) {
        // stage 64 validated ids for this wave (wave-private, in-order LDS)
        const int idraw = ids[pw + c + lane];
        const int mk    = mask[pw + c + lane];
        lid[w][lane] = (mk != 0 && (unsigned)idraw < KK) ? idraw : -1;

#pragma unroll
        for (int q = 0; q < 4; ++q) {         // 4 groups of 16 points
            const size_t P0 = pw + c + q * 16 + half * 8;
            const float* eb = emb + P0 * DD + d32;
            float xe[8];
#pragma unroll
            for (int e = 0; e < 8; ++e) xe[e] = eb[(size_t)e * DD];  // coalesced

            const int* lp = &lid[w][q * 16 + half * 8];
            bf16x8 bf, a0, a1;
#pragma unroll
            for (int e = 0; e < 8; ++e) {
                const int idv = lp[e];         // broadcast LDS read
                bf[e] = f2bf(xe[e]);
                const bool h0 = (idv == m0), h1 = (idv == m1);
                a0[e] = h0 ? (short)0x3F80 : (short)0;   // bf16 1.0
                a1[e] = h1 ? (short)0x3F80 : (short)0;
                c0 += h0 ? 1 : 0;
                c1 += h1 ? 1 : 0;
            }
            acc0 = __builtin_amdgcn_mfma_f32_32x32x16_bf16(a0, bf, acc0, 0, 0, 0);
            acc1 = __builtin_amdgcn_mfma_f32_32x32x16_bf16(a1, bf, acc1, 0, 0, 0);
        }
    }

    // write per-wave C fragments (verified C/D layout), every slot written once
#pragma unroll
    for (int r = 0; r < 16; ++r) {
        const int mrow = (r & 3) + 8 * (r >> 2) + 4 * half;
        lws[w][mrow][d32]      = acc0[r];
        lws[w][32 + mrow][d32] = acc1[r];
    }
    c0 += __shfl_down(c0, 32);
    c1 += __shfl_down(c1, 32);
    if (lane < 32) { lcnt[w][lane] = c0; lcnt[w][lane + 32] = c1; }
    __syncthreads();

    float* gs = sums + (size_t)b * KK * DD;
    for (int i = tid; i < KK * DD; i += 256) {
        const float s = ((const float*)lws[0])[i] + ((const float*)lws[1])[i]
                      + ((const float*)lws[2])[i] + ((const float*)lws[3])[i];
        atomicAdd(&gs[i], s);
    }
    if (tid < KK)
        atomicAdd(&counts[b * KK + tid],
                  (float)(lcnt[0][tid] + lcnt[1][tid] + lcnt[2][tid] + lcnt[3][tid]));
}

// ---------------------------------------------------------------------------
// Kernel 2: pull (variance) pass — unchanged from round 3 (fast, verified)
// ---------------------------------------------------------------------------
#define K2_BPB 64
#define K2_PTS (NN / K2_BPB)

__global__ __launch_bounds__(128) void k_pull(
    const float* __restrict__ emb, const int* __restrict__ ids,
    const int* __restrict__ mask, const float* __restrict__ sums,
    const float* __restrict__ counts, float* __restrict__ ipen)
{
    __shared__ float mu[DD][KK];
    __shared__ float lpp[128][KK + 1];
    const int tid = threadIdx.x;
    const int b   = blockIdx.x >> 6;
    const int blk = blockIdx.x & 63;

    const float* gs = sums + (size_t)b * KK * DD;
    const float* gc = counts + b * KK;
    for (int i = tid; i < KK * DD; i += 128) {
        const int k = i & 63, dd = i >> 6;
        mu[dd][k] = gs[k * DD + dd] / fmaxf(gc[k], 1.f);
    }
    for (int i = tid; i < 128 * (KK + 1); i += 128) ((float*)lpp)[i] = 0.f;
    __syncthreads();

    const size_t p0 = (size_t)b * NN + (size_t)blk * K2_PTS;
    float* myrow = lpp[tid];
    for (int p = tid; p < K2_PTS; p += 128) {
        const int id = ids[p0 + p];
        const bool v = (mask[p0 + p] != 0) && ((unsigned)id < KK);
        const int sid = v ? id : 0;
        const float4* e = (const float4*)(emb + (p0 + p) * DD);
        float dsq = 0.f;
#pragma unroll
        for (int q = 0; q < 8; ++q) {
            const float4 t = e[q];
            float a;
            a = t.x - mu[4 * q + 0][sid]; dsq = fmaf(a, a, dsq);
            a = t.y - mu[4 * q + 1][sid]; dsq = fmaf(a, a, dsq);
            a = t.z - mu[4 * q + 2][sid]; dsq = fmaf(a, a, dsq);
            a = t.w - mu[4 * q + 3][sid]; dsq = fmaf(a, a, dsq);
        }
        const float dist = (dsq > 0.f) ? sqrtf(dsq) : 0.f;
        float pen = fmaxf(dist - DELTA_V, 0.f);
        pen = pen * pen;
        if (v) myrow[sid] += pen;
    }
    __syncthreads();
    if (tid < KK) {
        float s = 0.f;
        for (int r = 0; r < 128; ++r) s += lpp[r][tid];
        atomicAdd(&ipen[b * KK + tid], s);
    }
}

// ---------------------------------------------------------------------------
// Kernel 3: per-batch reg loss + pairwise push loss (tiny)
// ---------------------------------------------------------------------------
__global__ __launch_bounds__(256) void k_push_reg(
    const float* __restrict__ sums, const float* __restrict__ counts,
    float* __restrict__ regb, float* __restrict__ distb)
{
    const int b = blockIdx.x;
    const int tid = threadIdx.x;
    __shared__ float lm[KK][DD + 1];
    __shared__ float lcnt[KK];
    __shared__ float red[4];

    if (tid < KK) lcnt[tid] = counts[b * KK + tid];
    __syncthreads();

    const float* gs = sums + (size_t)b * KK * DD;
    for (int i = tid; i < KK * DD; i += 256) {
        const int k = i >> 5, d = i & 31;
        lm[k][d] = gs[i] / fmaxf(lcnt[k], 1.f);
    }
    __syncthreads();

    float ninst = 0.f;
    if (tid < KK) {
        const float c = lcnt[tid];
        const float pres = (c > 0.f) ? 1.f : 0.f;
        float sq = 0.f;
#pragma unroll
        for (int d = 0; d < DD; ++d) { const float m = lm[tid][d]; sq = fmaf(m, m, sq); }
        float nm = ((sq > 0.f) ? sqrtf(sq) : 0.f) * pres;
        float pn = pres;
        for (int off = 32; off; off >>= 1) {
            pn += __shfl_down(pn, off);
            nm += __shfl_down(nm, off);
        }
        if (tid == 0) {
            ninst = pn;
            regb[b] = nm / fmaxf(pn, 1.f);
        }
    }

    float acc = 0.f;
    for (int idx = tid; idx < KK * KK; idx += 256) {
        const int i = idx >> 6, j = idx & 63;
        if (i < j && lcnt[i] > 0.f && lcnt[j] > 0.f) {
            float dsq = 0.f;
#pragma unroll
            for (int d = 0; d < DD; ++d) {
                const float df = lm[i][d] - lm[j][d];
                dsq = fmaf(df, df, dsq);
            }
            const float pd = (dsq > 0.f) ? sqrtf(dsq) : 0.f;
            const float pen = fmaxf(2.f * DELTA_D - pd, 0.f);
            acc = fmaf(pen, pen, acc);
        }
    }
    for (int off = 32; off; off >>= 1) acc += __shfl_down(acc, off);
    if ((tid & 63) == 0) red[tid >> 6] = acc;
    __syncthreads();
    if (tid == 0) {
        const float tot = red[0] + red[1] + red[2] + red[3];
        const float np = ninst * (ninst - 1.f) * 0.5f;
        distb[b] = tot / fmaxf(np, 1.f);
    }
}

// ---------------------------------------------------------------------------
// Kernel 4: final combine -> 4 outputs
// ---------------------------------------------------------------------------
__global__ __launch_bounds__(64) void k_final(
    const float* __restrict__ counts, const float* __restrict__ inst_pen,
    const float* __restrict__ regb, const float* __restrict__ distb,
    float* __restrict__ out)
{
    const int tid = threadIdx.x;
    __shared__ float s_var[BB], s_valid[BB];
    if (tid < BB) {
        const int b = tid;
        float vn = 0.f, ni = 0.f;
        for (int k = 0; k < KK; ++k) {
            const float c = counts[b * KK + k];
            if (c > 0.f) { ni += 1.f; vn += inst_pen[b * KK + k] / c; }
        }
        s_var[tid]   = vn / fmaxf(ni, 1.f);
        s_valid[tid] = (ni >= 2.f) ? 1.f : 0.f;
    }
    __syncthreads();
    if (tid == 0) {
        float denom = 0.f, v = 0.f, d = 0.f, r = 0.f;
        for (int b = 0; b < BB; ++b) {
            const float vb = s_valid[b];
            denom += vb;
            v += s_var[b] * vb;
            d += distb[b] * vb;
            r += regb[b] * vb;
        }
        denom = fmaxf(denom, 1.f);
        v /= denom; d /= denom; r /= denom;
        out[0] = v + d + 0.001f * r;   // ALPHA=BETA=1, GAMMA=0.001
        out[1] = v;
        out[2] = d;
        out[3] = r;
    }
}

// ---------------------------------------------------------------------------
extern "C" void kernel_launch(void* const* d_in, const int* in_sizes, int n_in,
                              void* d_out, int out_size, void* d_ws, size_t ws_size,
                              hipStream_t stream)
{
    const float* emb  = (const float*)d_in[0];
    const int*   ids  = (const int*)d_in[1];
    const int*   mask = (const int*)d_in[2];   // bool widened to int32

    float* ws     = (float*)d_ws;
    float* sums   = ws;                               // 32768
    float* counts = sums + (size_t)BB * KK * DD;      // 1024
    float* ipen   = counts + BB * KK;                 // 1024
    float* regb   = ipen + BB * KK;                   // 16
    float* distb  = regb + BB;                        // 16

    hipMemsetAsync(sums, 0, (size_t)(BB * KK * DD + 2 * BB * KK) * sizeof(float),
                   stream);

    k_accum<<<BB * K1_BPB, 256, 0, stream>>>(emb, ids, mask, sums, counts);
    k_pull<<<BB * K2_BPB, 128, 0, stream>>>(emb, ids, mask, sums, counts, ipen);
    k_push_reg<<<BB, 256, 0, stream>>>(sums, counts, regb, distb);
    k_final<<<1, 64, 0, stream>>>(counts, ipen, regb, distb, (float*)d_out);
}

// Round 5
// 94.347 us; speedup vs baseline: 2.5007x; 1.0482x over previous
//
#include <hip/hip_runtime.h>
#include <cstdint>

#define BB 16
#define NN 65536
#define DD 32
#define KK 64
#define DELTA_V 0.5f
#define DELTA_D 1.5f

typedef short bf16x8 __attribute__((ext_vector_type(8)));
typedef float f32x16 __attribute__((ext_vector_type(16)));

__device__ __forceinline__ short f2bf(float x) {
    union { float f; unsigned u; } v; v.f = x;
    const unsigned r = v.u + 0x7FFFu + ((v.u >> 16) & 1u);  // RNE
    return (short)(r >> 16);
}

__device__ __forceinline__ void gll16(const float* g, float* l) {
    __builtin_amdgcn_global_load_lds(
        (const __attribute__((address_space(1))) unsigned int*)g,
        (__attribute__((address_space(3))) unsigned int*)l, 16, 0, 0);
}

// ---------------------------------------------------------------------------
// Kernel 1: one-hot MFMA segment-sum into per-block partial tables.
// 1 wave/block; emb staged 4KB at a time via global_load_lds_dwordx4.
// parts[blk][64][32], pcnt[blk][64]  (plain coalesced stores, no atomics)
// ---------------------------------------------------------------------------
#define K1_BLOCKS 2048               // 128 per batch
#define K1_PPB 512                   // points per block

__global__ __launch_bounds__(64) void k_accum(
    const float* __restrict__ emb, const int* __restrict__ ids,
    const int* __restrict__ mask, float* __restrict__ parts,
    float* __restrict__ pcnt)
{
    __shared__ float ebuf[32][32];   // 4KB staging (32 points x 32 dims)
    const int lane = threadIdx.x;
    const int half = lane >> 5, d32 = lane & 31;
    const int blk  = blockIdx.x;
    const int b    = blk >> 7;                    // / 128
    const size_t p0 = (size_t)b * NN + (size_t)(blk & 127) * K1_PPB;

    f32x16 acc0 = {}, acc1 = {};
    int c0 = 0, c1 = 0;
    const int m0 = d32, m1 = d32 + 32;

    for (int s = 0; s < K1_PPB / 64; ++s) {       // 64-pt superchunks
        const size_t ps = p0 + s * 64;
        const int idr = ids[ps + lane];
        const int mkr = mask[ps + lane];
        const int vid = (mkr != 0 && (unsigned)idr < KK) ? idr : -1;
#pragma unroll
        for (int h = 0; h < 2; ++h) {             // 32-pt granules
            const float* gsrc = emb + (ps + h * 32) * DD;
#pragma unroll
            for (int i = 0; i < 4; ++i)
                gll16(gsrc + i * 256 + lane * 4, &ebuf[0][0] + i * 256);
            asm volatile("s_waitcnt vmcnt(0)" ::: "memory");
            __builtin_amdgcn_sched_barrier(0);
#pragma unroll
            for (int q = 0; q < 2; ++q) {         // 16 points per MFMA pair
                bf16x8 bfB, a0, a1;
#pragma unroll
                for (int e = 0; e < 8; ++e) {
                    const int pt = q * 16 + 8 * half + e;
                    bfB[e] = f2bf(ebuf[pt][d32]);
                    const int s_lo = __builtin_amdgcn_readlane(vid, h * 32 + q * 16 + e);
                    const int s_hi = __builtin_amdgcn_readlane(vid, h * 32 + q * 16 + 8 + e);
                    const int sel  = half ? s_hi : s_lo;
                    const bool h0 = (sel == m0), h1 = (sel == m1);
                    a0[e] = h0 ? (short)0x3F80 : (short)0;   // bf16 1.0
                    a1[e] = h1 ? (short)0x3F80 : (short)0;
                    c0 += h0 ? 1 : 0;
                    c1 += h1 ? 1 : 0;
                }
                acc0 = __builtin_amdgcn_mfma_f32_32x32x16_bf16(a0, bfB, acc0, 0, 0, 0);
                acc1 = __builtin_amdgcn_mfma_f32_32x32x16_bf16(a1, bfB, acc1, 0, 0, 0);
            }
        }
    }

    // write partial table (verified C/D layout), fully coalesced
    float* pb = parts + (size_t)blk * (KK * DD);
#pragma unroll
    for (int r = 0; r < 16; ++r) {
        const int mrow = (r & 3) + 8 * (r >> 2) + 4 * half;
        pb[mrow * DD + d32]        = acc0[r];
        pb[(32 + mrow) * DD + d32] = acc1[r];
    }
    c0 += __shfl_down(c0, 32);
    c1 += __shfl_down(c1, 32);
    if (lane < 32) {
        pcnt[(size_t)blk * KK + lane]      = (float)c0;
        pcnt[(size_t)blk * KK + 32 + lane] = (float)c1;
    }
}

// ---------------------------------------------------------------------------
// Kernel 2: fold 128 partials/batch -> means + counts:  mu[b][k][33]
//   (col 32 = count).  256 blocks x 128 threads, coalesced strided reads.
// ---------------------------------------------------------------------------
__global__ __launch_bounds__(128) void k_reduce(
    const float* __restrict__ parts, const float* __restrict__ pcnt,
    float* __restrict__ mu)
{
    const int b = blockIdx.x >> 4;        // / 16
    const int c = blockIdx.x & 15;        // elem chunk (128 elems)
    const int tid = threadIdx.x;
    __shared__ float t4[128][4];
    __shared__ float scnt[4];

    const float* pc = pcnt + (size_t)b * 128 * KK + c * 4;
#pragma unroll
    for (int u = 0; u < 4; ++u) t4[tid][u] = pc[(size_t)tid * KK + u];
    __syncthreads();
    if (tid < 4) {
        float s = 0.f;
        for (int j = 0; j < 128; ++j) s += t4[j][tid];
        scnt[tid] = s;
    }
    __syncthreads();

    const int e = c * 128 + tid;          // 0..2047
    const float* pp = parts + (size_t)b * 128 * (KK * DD) + e;
    float s = 0.f;
    for (int j = 0; j < 128; ++j) s += pp[(size_t)j * (KK * DD)];
    const int k = e >> 5, d = e & 31;
    const float cnt = scnt[tid >> 5];
    mu[(size_t)b * KK * 33 + k * 33 + d] = s / fmaxf(cnt, 1.f);
    if (tid < 4) mu[(size_t)b * KK * 33 + (c * 4 + tid) * 33 + 32] = scnt[tid];
}

// ---------------------------------------------------------------------------
// Kernel 3: pull (variance) pass.  pen^2/count folded per point -> scalar
// per-batch accumulator.  No per-k LDS table; one atomic per block.
// ---------------------------------------------------------------------------
#define K2_BPB 64
#define K2_PTS (NN / K2_BPB)             // 1024

__global__ __launch_bounds__(256) void k_pull(
    const float* __restrict__ emb, const int* __restrict__ ids,
    const int* __restrict__ mask, const float* __restrict__ mu,
    float* __restrict__ varacc)
{
    __shared__ float smu[KK * 33];
    __shared__ float red[4];
    const int tid = threadIdx.x;
    const int b   = blockIdx.x >> 6;
    const int blk = blockIdx.x & 63;

    const float* mub = mu + (size_t)b * KK * 33;
    for (int i = tid; i < KK * 33; i += 256) smu[i] = mub[i];
    __syncthreads();

    const size_t p0 = (size_t)b * NN + (size_t)blk * K2_PTS;
    float accv = 0.f;
    for (int p = tid; p < K2_PTS; p += 256) {
        const int id = ids[p0 + p];
        const bool v = (mask[p0 + p] != 0) && ((unsigned)id < KK);
        const int sid = v ? id : 0;
        const float* mr = smu + sid * 33;
        const float4* e = (const float4*)(emb + (p0 + p) * DD);
        float dsq = 0.f;
#pragma unroll
        for (int q = 0; q < 8; ++q) {
            const float4 t = e[q];
            float a;
            a = t.x - mr[4 * q + 0]; dsq = fmaf(a, a, dsq);
            a = t.y - mr[4 * q + 1]; dsq = fmaf(a, a, dsq);
            a = t.z - mr[4 * q + 2]; dsq = fmaf(a, a, dsq);
            a = t.w - mr[4 * q + 3]; dsq = fmaf(a, a, dsq);
        }
        const float dist = (dsq > 0.f) ? sqrtf(dsq) : 0.f;
        float pen = fmaxf(dist - DELTA_V, 0.f);
        pen = pen * pen;
        if (v) accv += pen / fmaxf(mr[32], 1.f);
    }
    for (int off = 32; off; off >>= 1) accv += __shfl_down(accv, off);
    if ((tid & 63) == 0) red[tid >> 6] = accv;
    __syncthreads();
    if (tid == 0) atomicAdd(&varacc[b], red[0] + red[1] + red[2] + red[3]);
}

// ---------------------------------------------------------------------------
// Kernel 4: per-batch reg loss + pairwise push loss (tiny), reads mu
// ---------------------------------------------------------------------------
__global__ __launch_bounds__(256) void k_push_reg(
    const float* __restrict__ mu, float* __restrict__ regb,
    float* __restrict__ distb)
{
    const int b = blockIdx.x;
    const int tid = threadIdx.x;
    __shared__ float lm[KK][DD + 1];
    __shared__ float lcnt[KK];
    __shared__ float red[4];

    const float* mub = mu + (size_t)b * KK * 33;
    for (int i = tid; i < KK * DD; i += 256) {
        const int k = i >> 5, d = i & 31;
        lm[k][d] = mub[k * 33 + d];
    }
    if (tid < KK) lcnt[tid] = mub[tid * 33 + 32];
    __syncthreads();

    float ninst = 0.f;
    if (tid < KK) {
        const float c = lcnt[tid];
        const float pres = (c > 0.f) ? 1.f : 0.f;
        float sq = 0.f;
#pragma unroll
        for (int d = 0; d < DD; ++d) { const float m = lm[tid][d]; sq = fmaf(m, m, sq); }
        float nm = ((sq > 0.f) ? sqrtf(sq) : 0.f) * pres;
        float pn = pres;
        for (int off = 32; off; off >>= 1) {
            pn += __shfl_down(pn, off);
            nm += __shfl_down(nm, off);
        }
        if (tid == 0) {
            ninst = pn;
            regb[b] = nm / fmaxf(pn, 1.f);
        }
    }

    float acc = 0.f;
    for (int idx = tid; idx < KK * KK; idx += 256) {
        const int i = idx >> 6, j = idx & 63;
        if (i < j && lcnt[i] > 0.f && lcnt[j] > 0.f) {
            float dsq = 0.f;
#pragma unroll
            for (int d = 0; d < DD; ++d) {
                const float df = lm[i][d] - lm[j][d];
                dsq = fmaf(df, df, dsq);
            }
            const float pd = (dsq > 0.f) ? sqrtf(dsq) : 0.f;
            const float pen = fmaxf(2.f * DELTA_D - pd, 0.f);
            acc = fmaf(pen, pen, acc);
        }
    }
    for (int off = 32; off; off >>= 1) acc += __shfl_down(acc, off);
    if ((tid & 63) == 0) red[tid >> 6] = acc;
    __syncthreads();
    if (tid == 0) {
        const float tot = red[0] + red[1] + red[2] + red[3];
        const float np = ninst * (ninst - 1.f) * 0.5f;
        distb[b] = tot / fmaxf(np, 1.f);
    }
}

// ---------------------------------------------------------------------------
// Kernel 5: final combine -> 4 outputs
// ---------------------------------------------------------------------------
__global__ __launch_bounds__(64) void k_final(
    const float* __restrict__ mu, const float* __restrict__ varacc,
    const float* __restrict__ regb, const float* __restrict__ distb,
    float* __restrict__ out)
{
    const int tid = threadIdx.x;
    __shared__ float s_var[BB], s_valid[BB];
    if (tid < BB) {
        const int b = tid;
        float ni = 0.f;
        for (int k = 0; k < KK; ++k)
            ni += (mu[(size_t)b * KK * 33 + k * 33 + 32] > 0.f) ? 1.f : 0.f;
        s_var[tid]   = varacc[b] / fmaxf(ni, 1.f);
        s_valid[tid] = (ni >= 2.f) ? 1.f : 0.f;
    }
    __syncthreads();
    if (tid == 0) {
        float denom = 0.f, v = 0.f, d = 0.f, r = 0.f;
        for (int b = 0; b < BB; ++b) {
            const float vb = s_valid[b];
            denom += vb;
            v += s_var[b] * vb;
            d += distb[b] * vb;
            r += regb[b] * vb;
        }
        denom = fmaxf(denom, 1.f);
        v /= denom; d /= denom; r /= denom;
        out[0] = v + d + 0.001f * r;   // ALPHA=BETA=1, GAMMA=0.001
        out[1] = v;
        out[2] = d;
        out[3] = r;
    }
}

// ---------------------------------------------------------------------------
extern "C" void kernel_launch(void* const* d_in, const int* in_sizes, int n_in,
                              void* d_out, int out_size, void* d_ws, size_t ws_size,
                              hipStream_t stream)
{
    const float* emb  = (const float*)d_in[0];
    const int*   ids  = (const int*)d_in[1];
    const int*   mask = (const int*)d_in[2];   // bool widened to int32

    float* ws     = (float*)d_ws;
    float* parts  = ws;                                     // 2048*2048
    float* pcnt   = parts + (size_t)K1_BLOCKS * KK * DD;    // 2048*64
    float* mu     = pcnt + (size_t)K1_BLOCKS * KK;          // 16*64*33
    float* varacc = mu + (size_t)BB * KK * 33;              // 16
    float* regb   = varacc + BB;                            // 16
    float* distb  = regb + BB;                              // 16

    hipMemsetAsync(varacc, 0, BB * sizeof(float), stream);

    k_accum<<<K1_BLOCKS, 64, 0, stream>>>(emb, ids, mask, parts, pcnt);
    k_reduce<<<BB * 16, 128, 0, stream>>>(parts, pcnt, mu);
    k_pull<<<BB * K2_BPB, 256, 0, stream>>>(emb, ids, mask, mu, varacc);
    k_push_reg<<<BB, 256, 0, stream>>>(mu, regb, distb);
    k_final<<<1, 64, 0, stream>>>(mu, varacc, regb, distb, (float*)d_out);
}